// Round 1
// baseline (529.840 us; speedup 1.0000x reference)
//
#include <hip/hip_runtime.h>
#include <hip/hip_bf16.h>
#include <math.h>

#define B_ 64
#define T_ 4096
#define C_ 256
#define H_ 4
#define HD_ 64
#define EPS_ 1e-5f

typedef __attribute__((ext_vector_type(4))) float floatx4;
typedef __attribute__((ext_vector_type(8))) short short8;   // 8 bf16 = 4 VGPRs (MFMA A/B frag)

__device__ __forceinline__ unsigned int pack_bf16x2(float a, float b) {
    unsigned int ua = __builtin_bit_cast(unsigned int, a);
    unsigned int ub = __builtin_bit_cast(unsigned int, b);
    ua = (ua + 0x7fffu + ((ua >> 16) & 1u)) >> 16;   // RNE
    ub = (ub + 0x7fffu + ((ub >> 16) & 1u)) >> 16;
    return ua | (ub << 16);
}

// ---------------- K0: W1 (H,C,HD) fp32 -> W1T[n][c] bf16, n = h*64+d ----------------
__global__ void k0_w1t(const float* __restrict__ W1, unsigned short* __restrict__ w1t) {
    int n = blockIdx.x;     // 256
    int c = threadIdx.x;    // 256
    int h = n >> 6, d = n & 63;
    float v = W1[(h * C_ + c) * HD_ + d];
    unsigned int u = __builtin_bit_cast(unsigned int, v);
    u = (u + 0x7fffu + ((u >> 16) & 1u)) >> 16;
    w1t[n * C_ + c] = (unsigned short)u;
}

// ---------------- K1: scores = tanh(x.W1 + b1) . w2 via bf16 MFMA ----------------
// grid 2048 (128 rows each), block 256 = 4 waves, wave w handles head w (64 n-cols).
__global__ __launch_bounds__(256, 2)
void k1_scores(const float* __restrict__ x, const unsigned short* __restrict__ w1t,
               const float* __restrict__ b1, const float* __restrict__ w2,
               float* __restrict__ scores) {
    __shared__ __align__(16) unsigned short shA[128 * 40];   // 128 rows x 32k, stride 40 (pad)
    __shared__ __align__(16) unsigned short shB[256 * 40];   // 256 n   x 32k, stride 40 (pad)

    const int tid  = threadIdx.x;
    const int lane = tid & 63;
    const int w    = tid >> 6;        // wave id == head id
    const int nl   = lane & 15;
    const int q    = lane >> 4;
    const int rowbase = blockIdx.x * 128;   // row = b*T + t

    floatx4 acc[8][4];
    #pragma unroll
    for (int i = 0; i < 8; ++i)
        #pragma unroll
        for (int j = 0; j < 4; ++j)
            acc[i][j] = (floatx4){0.f, 0.f, 0.f, 0.f};

    const int arow = tid >> 1;
    const int acol = (tid & 1) * 16;
    const float* xrow = x + (long)(rowbase + arow) * C_;

    for (int ks = 0; ks < 8; ++ks) {
        const int kb = ks * 32;
        // stage A: 128x32 fp32 -> bf16
        {
            const float4* p = (const float4*)(xrow + kb + acol);
            float4 f0 = p[0], f1 = p[1], f2 = p[2], f3 = p[3];
            uint4 u0, u1;
            u0.x = pack_bf16x2(f0.x, f0.y); u0.y = pack_bf16x2(f0.z, f0.w);
            u0.z = pack_bf16x2(f1.x, f1.y); u0.w = pack_bf16x2(f1.z, f1.w);
            u1.x = pack_bf16x2(f2.x, f2.y); u1.y = pack_bf16x2(f2.z, f2.w);
            u1.z = pack_bf16x2(f3.x, f3.y); u1.w = pack_bf16x2(f3.z, f3.w);
            uint4* dst = (uint4*)&shA[arow * 40 + acol];
            dst[0] = u0; dst[1] = u1;
        }
        // stage B: copy bf16 W1T slice (n = tid, 32 k)
        {
            const uint4* src = (const uint4*)(w1t + tid * C_ + kb);
            uint4 v0 = src[0], v1 = src[1], v2 = src[2], v3 = src[3];
            uint4* dst = (uint4*)&shB[tid * 40];
            dst[0] = v0; dst[1] = v1; dst[2] = v2; dst[3] = v3;
        }
        __syncthreads();

        short8 aFrag[8], bFrag[4];
        #pragma unroll
        for (int mb = 0; mb < 8; ++mb)
            aFrag[mb] = *(const short8*)&shA[(mb * 16 + nl) * 40 + q * 8];
        #pragma unroll
        for (int nb = 0; nb < 4; ++nb)
            bFrag[nb] = *(const short8*)&shB[(w * 64 + nb * 16 + nl) * 40 + q * 8];
        #pragma unroll
        for (int mb = 0; mb < 8; ++mb)
            #pragma unroll
            for (int nb = 0; nb < 4; ++nb)
                acc[mb][nb] = __builtin_amdgcn_mfma_f32_16x16x32_bf16(
                    aFrag[mb], bFrag[nb], acc[mb][nb], 0, 0, 0);
        __syncthreads();
    }

    // epilogue: s(t) = sum_d tanh(P + b1) * w2   (d = nb*16 + nl within head w)
    const int b = rowbase >> 12;          // / 4096
    const int tbase = rowbase & 4095;
    float b1v[4], w2v[4];
    #pragma unroll
    for (int nb = 0; nb < 4; ++nb) {
        int d = nb * 16 + nl;
        b1v[nb] = b1[w * HD_ + d];
        w2v[nb] = w2[w * HD_ + d];
    }
    #pragma unroll
    for (int mb = 0; mb < 8; ++mb) {
        float p[4];
        #pragma unroll
        for (int r = 0; r < 4; ++r) {
            float s = 0.f;
            #pragma unroll
            for (int nb = 0; nb < 4; ++nb) {
                float hv = tanhf(acc[mb][nb][r] + b1v[nb]);
                s += hv * w2v[nb];
            }
            p[r] = s;
        }
        #pragma unroll
        for (int m = 1; m < 16; m <<= 1)
            #pragma unroll
            for (int r = 0; r < 4; ++r)
                p[r] += __shfl_xor(p[r], m, 64);
        if (nl == 0) {
            #pragma unroll
            for (int r = 0; r < 4; ++r) {
                int tl = mb * 16 + q * 4 + r;
                scores[((long)(b * H_ + w)) * T_ + tbase + tl] = p[r];
            }
        }
    }
}

// ---------------- K2: softmax over T per (b,h) -> weights (into d_out) ----------------
__global__ void k2_softmax(const float* __restrict__ scores, float* __restrict__ weights) {
    __shared__ float red[256];
    int bh = blockIdx.x;
    int tid = threadIdx.x;
    const float* s = scores + (long)bh * T_;
    float loc[16];
    float m = -INFINITY;
    #pragma unroll
    for (int i = 0; i < 16; ++i) { loc[i] = s[tid + i * 256]; m = fmaxf(m, loc[i]); }
    red[tid] = m; __syncthreads();
    for (int st = 128; st > 0; st >>= 1) {
        if (tid < st) red[tid] = fmaxf(red[tid], red[tid + st]);
        __syncthreads();
    }
    m = red[0]; __syncthreads();
    float sum = 0.f;
    #pragma unroll
    for (int i = 0; i < 16; ++i) { loc[i] = expf(loc[i] - m); sum += loc[i]; }
    red[tid] = sum; __syncthreads();
    for (int st = 128; st > 0; st >>= 1) {
        if (tid < st) red[tid] += red[tid + st];
        __syncthreads();
    }
    float inv = 1.0f / red[0];
    float* wout = weights + (long)bh * T_;
    #pragma unroll
    for (int i = 0; i < 16; ++i) wout[tid + i * 256] = loc[i] * inv;
}

// ---------------- K3: context partials ctxp[b][tc][h][c] = sum_t w*x ----------------
__global__ void k3_ctx(const float* __restrict__ x, const float* __restrict__ weights,
                       float* __restrict__ ctxp) {
    __shared__ float wl[4 * 512];
    int bidx = blockIdx.x;          // b*8 + tc
    int b = bidx >> 3, tc = bidx & 7;
    int tid = threadIdx.x;          // = c
    int t0 = tc * 512;
    #pragma unroll
    for (int i = 0; i < 8; ++i) {
        int idx = tid + i * 256;
        int h = idx >> 9, tt = idx & 511;
        wl[idx] = weights[((long)(b * H_ + h)) * T_ + t0 + tt];
    }
    __syncthreads();
    float a0 = 0.f, a1 = 0.f, a2 = 0.f, a3 = 0.f;
    const float* xp = x + ((long)b * T_ + t0) * C_ + tid;
    #pragma unroll 8
    for (int tt = 0; tt < 512; ++tt) {
        float xv = xp[(long)tt * C_];
        a0 += wl[tt] * xv;
        a1 += wl[512 + tt] * xv;
        a2 += wl[1024 + tt] * xv;
        a3 += wl[1536 + tt] * xv;
    }
    float* o = ctxp + (long)bidx * 1024 + tid;
    o[0] = a0; o[256] = a1; o[512] = a2; o[768] = a3;
}

// ---------------- K4: combine partials + Wo projection + bias + LayerNorm ----------------
__global__ void k4_out(const float* __restrict__ ctxp, const float* __restrict__ Wo,
                       const float* __restrict__ bo, const float* __restrict__ gamma,
                       const float* __restrict__ beta, float* __restrict__ out) {
    __shared__ float multi[1024];
    __shared__ float red[256];
    int b = blockIdx.x, tid = threadIdx.x;
    #pragma unroll
    for (int j = 0; j < 4; ++j) {
        int idx = tid + j * 256;
        float s = 0.f;
        for (int tc = 0; tc < 8; ++tc) s += ctxp[((long)(b * 8 + tc)) * 1024 + idx];
        multi[idx] = s;
    }
    __syncthreads();
    float acc = bo[tid];
    const float4* wrow = (const float4*)(Wo + (long)tid * 1024);
    #pragma unroll 4
    for (int j4 = 0; j4 < 256; ++j4) {
        float4 wv = wrow[j4];
        acc += multi[j4 * 4] * wv.x + multi[j4 * 4 + 1] * wv.y +
               multi[j4 * 4 + 2] * wv.z + multi[j4 * 4 + 3] * wv.w;
    }
    red[tid] = acc; __syncthreads();
    for (int st = 128; st > 0; st >>= 1) {
        if (tid < st) red[tid] += red[tid + st];
        __syncthreads();
    }
    float mu = red[0] * (1.0f / 256.0f); __syncthreads();
    float dv = acc - mu;
    red[tid] = dv * dv; __syncthreads();
    for (int st = 128; st > 0; st >>= 1) {
        if (tid < st) red[tid] += red[tid + st];
        __syncthreads();
    }
    float var = red[0] * (1.0f / 256.0f);
    out[(long)b * C_ + tid] = dv * rsqrtf(var + EPS_) * gamma[tid] + beta[tid];
}

extern "C" void kernel_launch(void* const* d_in, const int* in_sizes, int n_in,
                              void* d_out, int out_size, void* d_ws, size_t ws_size,
                              hipStream_t stream) {
    const float* x     = (const float*)d_in[0];
    const float* W1    = (const float*)d_in[1];
    const float* b1    = (const float*)d_in[2];
    const float* w2    = (const float*)d_in[3];
    const float* Wo    = (const float*)d_in[4];
    const float* bo    = (const float*)d_in[5];
    const float* gamma = (const float*)d_in[6];
    const float* beta  = (const float*)d_in[7];

    float* out     = (float*)d_out;          // (B,C) = 16384 floats
    float* weights = out + B_ * C_;          // (B,H,T) = 1048576 floats

    float* scores = (float*)d_ws;                              // B*H*T fp32 (4 MiB)
    float* ctxp   = scores + (long)B_ * H_ * T_;               // 64*8*1024 fp32 (2 MiB)
    unsigned short* w1t = (unsigned short*)(ctxp + 64 * 8 * 1024); // 65536 bf16 (128 KiB)

    k0_w1t   <<<256, 256, 0, stream>>>(W1, w1t);
    k1_scores<<<2048, 256, 0, stream>>>(x, w1t, b1, w2, scores);
    k2_softmax<<<256, 256, 0, stream>>>(scores, weights);
    k3_ctx   <<<512, 256, 0, stream>>>(x, weights, ctxp);
    k4_out   <<<64, 256, 0, stream>>>(ctxp, Wo, bo, gamma, beta, out);
}

// Round 2
// 487.208 us; speedup vs baseline: 1.0875x; 1.0875x over previous
//
#include <hip/hip_runtime.h>
#include <hip/hip_bf16.h>
#include <math.h>

#define B_ 64
#define T_ 4096
#define C_ 256
#define H_ 4
#define HD_ 64
#define EPS_ 1e-5f

typedef __attribute__((ext_vector_type(4))) float floatx4;
typedef __attribute__((ext_vector_type(8))) short short8;   // 8 bf16 = 4 VGPRs (MFMA A/B frag)

__device__ __forceinline__ unsigned int pack_bf16x2(float a, float b) {
    unsigned int ua = __builtin_bit_cast(unsigned int, a);
    unsigned int ub = __builtin_bit_cast(unsigned int, b);
    ua = (ua + 0x7fffu + ((ua >> 16) & 1u)) >> 16;   // RNE
    ub = (ub + 0x7fffu + ((ub >> 16) & 1u)) >> 16;
    return ua | (ub << 16);
}

// ---------------- K0: W1 (H,C,HD) fp32 -> W1T[n][c] bf16, n = h*64+d ----------------
__global__ void k0_w1t(const float* __restrict__ W1, unsigned short* __restrict__ w1t) {
    int n = blockIdx.x;     // 256
    int c = threadIdx.x;    // 256
    int h = n >> 6, d = n & 63;
    float v = W1[(h * C_ + c) * HD_ + d];
    unsigned int u = __builtin_bit_cast(unsigned int, v);
    u = (u + 0x7fffu + ((u >> 16) & 1u)) >> 16;
    w1t[n * C_ + c] = (unsigned short)u;
}

// ---------------- K1 fused: scores (MFMA) + partial softmax + partial context ----------------
// grid 4096 (64 rows each), block 256 = 4 waves, wave w = head w.
// Outputs: rawscore (into weights output buf), ctxp[blk][h][c], mS[blk][h][{m,S}].
__global__ __launch_bounds__(256, 3)
void k1_fused(const float* __restrict__ x, const unsigned short* __restrict__ w1t,
              const float* __restrict__ b1, const float* __restrict__ w2,
              float* __restrict__ rawscore, float* __restrict__ ctxp,
              float* __restrict__ mS) {
    __shared__ __align__(16) unsigned short shA[64 * 40];    // 64 rows x 32k, stride 40 (pad)
    __shared__ __align__(16) unsigned short shB[256 * 40];   // 256 n   x 32k, stride 40 (pad)
    __shared__ float sS[4 * 64];   // raw scores per head
    __shared__ float sP[4 * 64];   // exp(s - m_loc) per head

    const int tid  = threadIdx.x;
    const int lane = tid & 63;
    const int w    = tid >> 6;        // wave id == head id
    const int nl   = lane & 15;
    const int q    = lane >> 4;
    const int rowbase = blockIdx.x * 64;       // row = b*T + t
    const int b       = blockIdx.x >> 6;       // 64 blocks per batch
    const int tbase   = (blockIdx.x & 63) * 64;

    floatx4 acc[4][4];
    #pragma unroll
    for (int i = 0; i < 4; ++i)
        #pragma unroll
        for (int j = 0; j < 4; ++j)
            acc[i][j] = (floatx4){0.f, 0.f, 0.f, 0.f};

    const int arow = tid >> 2;          // 0..63
    const int acol = (tid & 3) * 8;     // 0,8,16,24
    const float* aptr = x + (long)(rowbase + arow) * C_ + acol;
    const unsigned short* bptr = w1t + tid * C_;

    // register prefetch of chunk 0
    float4 fa0 = ((const float4*)aptr)[0];
    float4 fa1 = ((const float4*)aptr)[1];
    uint4  fb0 = ((const uint4*)bptr)[0];
    uint4  fb1 = ((const uint4*)bptr)[1];
    uint4  fb2 = ((const uint4*)bptr)[2];
    uint4  fb3 = ((const uint4*)bptr)[3];

    for (int ks = 0; ks < 8; ++ks) {
        // store staged chunk (regs -> LDS), bf16 pack for A
        uint4 ua;
        ua.x = pack_bf16x2(fa0.x, fa0.y); ua.y = pack_bf16x2(fa0.z, fa0.w);
        ua.z = pack_bf16x2(fa1.x, fa1.y); ua.w = pack_bf16x2(fa1.z, fa1.w);
        *(uint4*)&shA[arow * 40 + acol] = ua;
        uint4* bd = (uint4*)&shB[tid * 40];
        bd[0] = fb0; bd[1] = fb1; bd[2] = fb2; bd[3] = fb3;
        __syncthreads();
        // prefetch next chunk while MFMAs run
        if (ks < 7) {
            const float4* ap = (const float4*)(aptr + (ks + 1) * 32);
            fa0 = ap[0]; fa1 = ap[1];
            const uint4* bp = (const uint4*)(bptr + (ks + 1) * 32);
            fb0 = bp[0]; fb1 = bp[1]; fb2 = bp[2]; fb3 = bp[3];
        }
        short8 aF[4], bF[4];
        #pragma unroll
        for (int mb = 0; mb < 4; ++mb)
            aF[mb] = *(const short8*)&shA[(mb * 16 + nl) * 40 + q * 8];
        #pragma unroll
        for (int nb = 0; nb < 4; ++nb)
            bF[nb] = *(const short8*)&shB[(w * 64 + nb * 16 + nl) * 40 + q * 8];
        #pragma unroll
        for (int mb = 0; mb < 4; ++mb)
            #pragma unroll
            for (int nb = 0; nb < 4; ++nb)
                acc[mb][nb] = __builtin_amdgcn_mfma_f32_16x16x32_bf16(
                    aF[mb], bF[nb], acc[mb][nb], 0, 0, 0);
        __syncthreads();
    }

    // epilogue: s(t) = sum_d tanh(P + b1)*w2  (d = nb*16 + nl, t = mb*16 + q*4 + r)
    float b1v[4], w2v[4];
    #pragma unroll
    for (int nb = 0; nb < 4; ++nb) {
        int d = nb * 16 + nl;
        b1v[nb] = b1[w * HD_ + d];
        w2v[nb] = w2[w * HD_ + d];
    }
    #pragma unroll
    for (int mb = 0; mb < 4; ++mb) {
        float p[4];
        #pragma unroll
        for (int r = 0; r < 4; ++r) {
            float s = 0.f;
            #pragma unroll
            for (int nb = 0; nb < 4; ++nb)
                s += tanhf(acc[mb][nb][r] + b1v[nb]) * w2v[nb];
            p[r] = s;
        }
        #pragma unroll
        for (int m = 1; m < 16; m <<= 1)
            #pragma unroll
            for (int r = 0; r < 4; ++r)
                p[r] += __shfl_xor(p[r], m, 64);
        if (nl == 0) {
            #pragma unroll
            for (int r = 0; r < 4; ++r)
                sS[w * 64 + mb * 16 + q * 4 + r] = p[r];
        }
    }

    // phase 2: per-head local softmax partials over this block's 64 t values
    {
        float s = sS[w * 64 + lane];
        float m = s;
        #pragma unroll
        for (int off = 1; off < 64; off <<= 1)
            m = fmaxf(m, __shfl_xor(m, off, 64));
        float e = expf(s - m);
        float Ss = e;
        #pragma unroll
        for (int off = 1; off < 64; off <<= 1)
            Ss += __shfl_xor(Ss, off, 64);
        sP[w * 64 + lane] = e;
        rawscore[((long)(b * H_ + w)) * T_ + tbase + lane] = s;
        if (lane == 0) {
            mS[((long)blockIdx.x * H_ + w) * 2 + 0] = m;
            mS[((long)blockIdx.x * H_ + w) * 2 + 1] = Ss;
        }
    }
    __syncthreads();

    // phase 3: partial contexts ctx_loc[h][c] = sum_t p[h][t] * x[t][c]  (x re-read, L2-hot)
    {
        float c0 = 0.f, c1 = 0.f, c2 = 0.f, c3 = 0.f;
        const float* xr = x + (long)rowbase * C_ + tid;
        #pragma unroll 8
        for (int t = 0; t < 64; ++t) {
            float xv = xr[(long)t * C_];
            c0 += sP[t] * xv;
            c1 += sP[64 + t] * xv;
            c2 += sP[128 + t] * xv;
            c3 += sP[192 + t] * xv;
        }
        float* o = ctxp + (long)blockIdx.x * (H_ * C_) + tid;
        o[0]   = c0;
        o[256] = c1;
        o[512] = c2;
        o[768] = c3;
    }
}

// ---------------- K2: combine partials -> weights (in-place over raw scores) + multi ----------------
__global__ void k2_combine(const float* __restrict__ ctxp, const float* __restrict__ mS,
                           float* __restrict__ weights, float* __restrict__ multi) {
    __shared__ float sm[64], sSl[64], sc[64];
    int bh = blockIdx.x;              // b*H + h
    int b = bh >> 2, h = bh & 3;
    int tid = threadIdx.x;
    if (tid < 64) {
        long blk = (long)b * 64 + tid;
        sm[tid]  = mS[(blk * H_ + h) * 2 + 0];
        sSl[tid] = mS[(blk * H_ + h) * 2 + 1];
    }
    __syncthreads();
    float m = -INFINITY;
    #pragma unroll 8
    for (int j = 0; j < 64; ++j) m = fmaxf(m, sm[j]);
    if (tid < 64) sc[tid] = expf(sm[tid] - m);
    __syncthreads();
    float S = 0.f;
    #pragma unroll 8
    for (int j = 0; j < 64; ++j) S += sSl[j] * sc[j];
    float invS = 1.0f / S;

    float acc = 0.f;
    #pragma unroll 4
    for (int j = 0; j < 64; ++j)
        acc += ctxp[((long)(b * 64 + j) * H_ + h) * C_ + tid] * sc[j];
    multi[(long)b * (H_ * C_) + h * C_ + tid] = acc * invS;

    float* wr = weights + (long)bh * T_;
    #pragma unroll
    for (int i = 0; i < 16; ++i) {
        int t = tid + i * 256;
        float sv = wr[t];                 // raw score written by k1_fused
        wr[t] = expf(sv - m) * invS;
    }
}

// ---------------- K4: Wo projection + bias + LayerNorm ----------------
__global__ void k4_out(const float* __restrict__ multiG, const float* __restrict__ Wo,
                       const float* __restrict__ bo, const float* __restrict__ gamma,
                       const float* __restrict__ beta, float* __restrict__ out) {
    __shared__ float multi[1024];
    __shared__ float red[256];
    int b = blockIdx.x, tid = threadIdx.x;
    #pragma unroll
    for (int j = 0; j < 4; ++j) {
        int idx = tid + j * 256;
        multi[idx] = multiG[(long)b * 1024 + idx];
    }
    __syncthreads();
    float acc = bo[tid];
    const float4* wrow = (const float4*)(Wo + (long)tid * 1024);
    #pragma unroll 4
    for (int j4 = 0; j4 < 256; ++j4) {
        float4 wv = wrow[j4];
        acc += multi[j4 * 4] * wv.x + multi[j4 * 4 + 1] * wv.y +
               multi[j4 * 4 + 2] * wv.z + multi[j4 * 4 + 3] * wv.w;
    }
    red[tid] = acc; __syncthreads();
    for (int st = 128; st > 0; st >>= 1) {
        if (tid < st) red[tid] += red[tid + st];
        __syncthreads();
    }
    float mu = red[0] * (1.0f / 256.0f); __syncthreads();
    float dv = acc - mu;
    red[tid] = dv * dv; __syncthreads();
    for (int st = 128; st > 0; st >>= 1) {
        if (tid < st) red[tid] += red[tid + st];
        __syncthreads();
    }
    float var = red[0] * (1.0f / 256.0f);
    out[(long)b * C_ + tid] = dv * rsqrtf(var + EPS_) * gamma[tid] + beta[tid];
}

extern "C" void kernel_launch(void* const* d_in, const int* in_sizes, int n_in,
                              void* d_out, int out_size, void* d_ws, size_t ws_size,
                              hipStream_t stream) {
    const float* x     = (const float*)d_in[0];
    const float* W1    = (const float*)d_in[1];
    const float* b1    = (const float*)d_in[2];
    const float* w2    = (const float*)d_in[3];
    const float* Wo    = (const float*)d_in[4];
    const float* bo    = (const float*)d_in[5];
    const float* gamma = (const float*)d_in[6];
    const float* beta  = (const float*)d_in[7];

    float* out     = (float*)d_out;          // (B,C) = 16384 floats
    float* weights = out + B_ * C_;          // (B,H,T) = 1048576 floats (holds raw scores first)

    // workspace: ctxp 4096*4*256 fp32 (16 MiB) + mS 4096*4*2 + multi 64*1024 + w1t
    float* ctxp  = (float*)d_ws;
    float* mS    = ctxp + (long)4096 * H_ * C_;
    float* multi = mS + (long)4096 * H_ * 2;
    unsigned short* w1t = (unsigned short*)(multi + B_ * H_ * C_);

    k0_w1t    <<<256, 256, 0, stream>>>(W1, w1t);
    k1_fused  <<<4096, 256, 0, stream>>>(x, w1t, b1, w2, weights, ctxp, mS);
    k2_combine<<<256, 256, 0, stream>>>(ctxp, mS, weights, multi);
    k4_out    <<<64, 256, 0, stream>>>(multi, Wo, bo, gamma, beta, out);
}